// Round 5
// baseline (880.381 us; speedup 1.0000x reference)
//
#include <hip/hip_runtime.h>
#include <cstdint>
#include <cstddef>

typedef _Float16 f16;
typedef __attribute__((ext_vector_type(8))) f16 f16x8;
typedef __attribute__((ext_vector_type(4))) f16 f16x4;
typedef __attribute__((ext_vector_type(4))) float f32x4;

#define M_TOK 8192
#define DDIM 1024
#define HDIM 4096
#define NEXP 4
#define TOTPAD 17408  // >= 16384 + 4*255 (BM=256 padding), and >= GX*256

// async global->LDS, 16B per lane (LDS dest = wave-uniform base + lane*16).
__device__ __forceinline__ void async_copy16(const void* g, void* s) {
    __builtin_amdgcn_global_load_lds((__attribute__((address_space(1))) void*)g,
                                     (__attribute__((address_space(3))) void*)s,
                                     16, 0, 0);
}

// inline-asm ds_read_b128 (keeps compiler aliasing model away from in-flight
// global_load_lds; ordering vs MFMA via lgkmcnt(0)+sched_barrier(0), rule #18).
__device__ __forceinline__ f16x8 ds_read_b128_f16(uint32_t addr) {
    f16x8 r;
    asm volatile("ds_read_b128 %0, %1" : "=v"(r) : "v"(addr));
    return r;
}
__device__ __forceinline__ uint32_t lds_addr(const void* p) {
    return (uint32_t)(uintptr_t)(__attribute__((address_space(3))) const void*)p;
}

// stage one 16-KiB A k-plane (256 rows x 32 f16) = 4 global_load_lds / thread
// (256 threads; 4 row-groups of 64). ga[g] pre-includes the inverse-swizzle.
__device__ __forceinline__ void stageA(const f16* const* ga, int koff,
                                       f16* plane, int tid) {
#pragma unroll
    for (int g = 0; g < 4; ++g)
        async_copy16(ga[g] + koff, plane + g * 2048 + tid * 8);
}

// ------- Router: logits -> top2 softmax weights; also writes xb (f16) ------
__global__ __launch_bounds__(256) void router_kernel(
    const float* __restrict__ x, const float* __restrict__ Wr,
    float* __restrict__ wts, int* __restrict__ top2, f16* __restrict__ xb) {
    __shared__ float wr_s[DDIM * NEXP];
    for (int i = threadIdx.x; i < DDIM * NEXP; i += 256) wr_s[i] = Wr[i];
    __syncthreads();
    const int wave = threadIdx.x >> 6, lane = threadIdx.x & 63;
    const int t = blockIdx.x * 4 + wave;
    float a0 = 0.f, a1 = 0.f, a2 = 0.f, a3 = 0.f;
    const float* xr = x + (size_t)t * DDIM;
    f16* xo = xb + (size_t)t * DDIM;
    for (int i = 0; i < DDIM; i += 256) {
        const int d = i + lane * 4;
        const float4 v = *(const float4*)(xr + d);
        f16x4 o = {(f16)v.x, (f16)v.y, (f16)v.z, (f16)v.w};
        *(f16x4*)(xo + d) = o;  // fused fp32->f16 conversion
        const float* w0 = &wr_s[d * 4];
        a0 += v.x * w0[0] + v.y * w0[4] + v.z * w0[8]  + v.w * w0[12];
        a1 += v.x * w0[1] + v.y * w0[5] + v.z * w0[9]  + v.w * w0[13];
        a2 += v.x * w0[2] + v.y * w0[6] + v.z * w0[10] + v.w * w0[14];
        a3 += v.x * w0[3] + v.y * w0[7] + v.z * w0[11] + v.w * w0[15];
    }
    for (int off = 32; off > 0; off >>= 1) {
        a0 += __shfl_xor(a0, off, 64);
        a1 += __shfl_xor(a1, off, 64);
        a2 += __shfl_xor(a2, off, 64);
        a3 += __shfl_xor(a3, off, 64);
    }
    if (lane == 0) {
        float lg[4] = {a0, a1, a2, a3};
        int i1 = 0;
        for (int e = 1; e < 4; ++e) if (lg[e] > lg[i1]) i1 = e;
        int i2 = -1;
        for (int e = 0; e < 4; ++e) {
            if (e == i1) continue;
            if (i2 < 0 || lg[e] > lg[i2]) i2 = e;
        }
        const float w1 = 1.0f / (1.0f + expf(lg[i2] - lg[i1]));
        float w[4] = {0.f, 0.f, 0.f, 0.f};
        w[i1] = w1; w[i2] = 1.0f - w1;
        float* o = wts + (size_t)t * 4;
        o[0] = w[0]; o[1] = w[1]; o[2] = w[2]; o[3] = w[3];
        top2[t] = i1 | (i2 << 8);
    }
}

// ---------------- count / offsets / fill (sparse routing lists) -----------
__global__ __launch_bounds__(256) void count_kernel(
    const int* __restrict__ top2, int* __restrict__ meta) {
    __shared__ int lc[4];
    if (threadIdx.x < 4) lc[threadIdx.x] = 0;
    __syncthreads();
    const int t = blockIdx.x * 256 + threadIdx.x;
    const int p = top2[t];
    atomicAdd(&lc[p & 0xff], 1);
    atomicAdd(&lc[(p >> 8) & 0xff], 1);
    __syncthreads();
    if (threadIdx.x < 4) atomicAdd(&meta[threadIdx.x], lc[threadIdx.x]);
}

__global__ void offsets_kernel(int* __restrict__ meta) {
    if (threadIdx.x == 0) {
        int off = 0;
        for (int e = 0; e < 4; ++e) {
            const int c = meta[e];
            const int cp = (c + 255) & ~255;  // 256-pad for BM=256
            meta[4 + e] = cp;   // padded count
            meta[8 + e] = off;  // segment offset
            off += cp;
        }
    }
}

__global__ __launch_bounds__(256) void fill_kernel(
    const int* __restrict__ top2, int* __restrict__ meta,
    int* __restrict__ toklist) {
    __shared__ int lc[4], base[4];
    if (threadIdx.x < 4) lc[threadIdx.x] = 0;
    __syncthreads();
    const int t = blockIdx.x * 256 + threadIdx.x;
    const int p = top2[t];
    const int e1 = p & 0xff, e2 = (p >> 8) & 0xff;
    const int r1 = atomicAdd(&lc[e1], 1);
    const int r2 = atomicAdd(&lc[e2], 1);
    __syncthreads();
    if (threadIdx.x < 4) base[threadIdx.x] = atomicAdd(&meta[12 + threadIdx.x], lc[threadIdx.x]);
    __syncthreads();
    toklist[meta[8 + e1] + base[e1] + r1] = t;
    toklist[meta[8 + e2] + base[e2] + r2] = t;
}

// -- pack W [K][N] fp32 -> fragment-major f16 B (per z-expert) --------------
// (verbatim from the verified baseline) B[n][k] = W[k][n]; f16 index:
//   I(n,k) = (n16*(K/64) + k0b)*1024 + kk2*512 + quad*128 + l16*8 + j
// so a wave's B-fragment load is frag_base + lane*16B (perfectly coalesced).
__global__ __launch_bounds__(256) void pack_b_kernel(
    const float* __restrict__ in0, f16* __restrict__ out0, int K, int N) {
    __shared__ float tile[64][65];
    const float* in = in0 + (size_t)blockIdx.z * K * N;
    f16* out = out0 + (size_t)blockIdx.z * K * N;
    const int n0 = blockIdx.x * 64, k0 = blockIdx.y * 64;
    const int tx = threadIdx.x & 63, ty = threadIdx.x >> 6;  // ty 0..3
#pragma unroll
    for (int i = 0; i < 64; i += 4)
        tile[ty + i][tx] = in[(size_t)(k0 + ty + i) * N + n0 + tx];
    __syncthreads();
#pragma unroll
    for (int c = 0; c < 2; ++c) {                   // 512 chunks total
        const int cc = c * 256 + threadIdx.x;       // 0..511: 16B chunk id
        const int grp = cc >> 7;                    // n-16-group (0..3)
        const int within = cc & 127;
        const int kk2 = within >> 6, quad = (within >> 4) & 3, l16 = within & 15;
        const int nl = grp * 16 + l16;
        const int kl = kk2 * 32 + quad * 8;
        f16x8 v;
#pragma unroll
        for (int j = 0; j < 8; ++j) v[j] = (f16)tile[kl + j][nl];
        const size_t o = ((size_t)(n0 / 16 + grp) * (K >> 6) + (k0 >> 6)) * 1024 +
                         (size_t)within * 8;
        *(f16x8*)&out[o] = v;
    }
}

// -- 256x128 GEMM, BK=64, 4 waves (wave-tile 128x64), A-LDS dbuf (64 KiB) ---
//    + B from registers (fragment-major pack), 2 blocks/CU.
// Rationale (r4 post-mortem): wave-tile 128x64 => LDS-read ratio 0.375
// (balanced vs MFMA); B-in-reg keeps LDS at 64 KiB => 2 blocks/CU so block
// A's MFMA overlaps block B's read/stage phases.  2 phases/K-tile, counted
// vmcnt(8) per tile keeps 8 A-loads in flight across barriers; B-reg loads
// get compiler-inserted waits (FIFO vmcnt => they also guarantee older
// A-plane loads).  Swizzle both-sides: chunk ^= (row>>1)&3.
// MODE 0 (SPLIT=1): outH[off+m] = relu(A_gather x B + b1)   (f16, h)
// MODE 1: atomicAdd(out[tok], wts[tok][e] * (A x B + (kh==0 ? b2 : 0)))
template <int MODE, int SPLIT>
__global__ __launch_bounds__(256, 2) void gemm_kernel(
    const f16* __restrict__ A, const f16* __restrict__ Bf, int N, int K,
    const float* __restrict__ bias, f16* __restrict__ outH, float* __restrict__ outF,
    const float* __restrict__ wts, const int* __restrict__ toklist,
    const int* __restrict__ meta, int e0) {
    __shared__ __align__(16) f16 S[2][16384];  // 64 KiB: 2 bufs x (A_k0 + A_k1)
    const int zz = blockIdx.z / SPLIT, kh = blockIdx.z % SPLIT;
    const int e = e0 + zz;
    const int m0 = blockIdx.x * 256, n0 = blockIdx.y * 128;
    int cnt = M_TOK, cp = M_TOK, off = 0;
    if (meta) { cnt = meta[e]; cp = meta[4 + e]; off = meta[8 + e]; }
    if (m0 >= cp) return;

    const int Kb = K >> 6;
    const int NT = (K / SPLIT) >> 6;
    const int kb0 = kh * NT;

    const f16* Be = Bf + (size_t)zz * N * K;
    const float* be = bias + (size_t)zz * N;

    const int tid = threadIdx.x;
    const int wave = tid >> 6, lane = tid & 63;
    const int wm = wave >> 1, wn = wave & 1;      // 2M x 2N waves, 128x64 each
    const int quad = lane >> 4, l16 = lane & 15;

    // A staging: 4 row-groups of 64 rows; inverse-swizzled chunk
    const int r0 = tid >> 2;                              // 0..63
    const int gswz = ((tid & 3) ^ ((r0 >> 1) & 3)) * 8;   // f16 units
    const f16* ga[4];
#pragma unroll
    for (int g = 0; g < 4; ++g) {
        const int gm = m0 + g * 64 + r0;
        int arow;
        if (MODE == 0) arow = toklist ? toklist[off + gm] : gm;
        else arow = off + gm;
        ga[g] = A + (size_t)arow * K + (size_t)kb0 * 64 + gswz;
    }
    // B fragment pointers: frag(j, k0b, kk2) = bp[j] + k0b*1024 + kk2*512
    const f16* bp[4];
#pragma unroll
    for (int j = 0; j < 4; ++j)
        bp[j] = Be + ((size_t)(n0 / 16 + wn * 4 + j) * Kb) * 1024 + lane * 8;

    const int chq = ((quad ^ ((l16 >> 1) & 3)) << 3);
    const uint32_t sb0 = lds_addr(&S[0][0]), sb1 = lds_addr(&S[1][0]);
    const uint32_t a_b = (uint32_t)(((wm * 128 + l16) * 32 + chq) * 2);

    f32x4 acc[8][4] = {};

    // prologue: A(0) both k-planes -> S0; A(1) k0 -> S1
    stageA(ga, 0,  S[0] + 0,    tid);
    stageA(ga, 32, S[0] + 8192, tid);
    if (NT > 1) {
        stageA(ga, 64, S[1] + 0, tid);
        asm volatile("s_waitcnt vmcnt(4)" ::: "memory");  // A(0) landed
    } else {
        asm volatile("s_waitcnt vmcnt(0)" ::: "memory");
    }
    __builtin_amdgcn_s_barrier();

    int p = 0;
#pragma unroll 1
    for (int t = 0; t < NT; ++t) {
        const uint32_t sp = p ? sb1 : sb0;
        f16* SpW = S[p];
        f16* SoW = S[p ^ 1];
        f16x8 af[8], bfv[4];
        // ---- phase 0 (kk2=0): B(t)k0 -> regs; A_k0(p) -> frags;
        //      stage A_k1(t+1) -> other buf (its plane was read at t-1 ph1)
#pragma unroll
        for (int j = 0; j < 4; ++j)
            bfv[j] = *(const f16x8*)(bp[j] + ((size_t)(kb0 + t) << 10));
#pragma unroll
        for (int i = 0; i < 8; ++i) af[i] = ds_read_b128_f16(sp + a_b + i * 1024);
        if (t + 1 < NT) stageA(ga, ((t + 1) << 6) + 32, SoW + 8192, tid);
        __builtin_amdgcn_s_barrier();
        asm volatile("s_waitcnt lgkmcnt(0)" ::: "memory");
        __builtin_amdgcn_sched_barrier(0);
        __builtin_amdgcn_s_setprio(1);
#pragma unroll
        for (int i = 0; i < 8; ++i)
#pragma unroll
            for (int j = 0; j < 4; ++j)
                acc[i][j] = __builtin_amdgcn_mfma_f32_16x16x32_f16(af[i], bfv[j], acc[i][j], 0, 0, 0);
        __builtin_amdgcn_s_setprio(0);
        __builtin_amdgcn_s_barrier();
        // ---- phase 1 (kk2=1): B(t)k1 -> regs; A_k1(p) -> frags;
        //      stage A_k0(t+2) -> this buf (read at ph0, barrier since)
#pragma unroll
        for (int j = 0; j < 4; ++j)
            bfv[j] = *(const f16x8*)(bp[j] + ((size_t)(kb0 + t) << 10) + 512);
#pragma unroll
        for (int i = 0; i < 8; ++i)
            af[i] = ds_read_b128_f16(sp + a_b + 16384 + i * 1024);
        if (t + 2 < NT) stageA(ga, (t + 2) << 6, SpW, tid);
        __builtin_amdgcn_s_barrier();
        asm volatile("s_waitcnt lgkmcnt(0)" ::: "memory");
        __builtin_amdgcn_sched_barrier(0);
        __builtin_amdgcn_s_setprio(1);
#pragma unroll
        for (int i = 0; i < 8; ++i)
#pragma unroll
            for (int j = 0; j < 4; ++j)
                acc[i][j] = __builtin_amdgcn_mfma_f32_16x16x32_f16(af[i], bfv[j], acc[i][j], 0, 0, 0);
        __builtin_amdgcn_s_setprio(0);
        // counted drain: keep this tile's 8 stage-loads in flight, force
        // A(t+1) planes complete before next tile reads them.
        if (t + 1 < NT) {
            if (t + 2 < NT) asm volatile("s_waitcnt vmcnt(8)" ::: "memory");
            else            asm volatile("s_waitcnt vmcnt(4)" ::: "memory");
            __builtin_amdgcn_s_barrier();
        }
        p ^= 1;
    }

    // epilogue: C/D layout col = lane&15, row = quad*4 + reg
#pragma unroll
    for (int i = 0; i < 8; ++i) {
        const int mb = m0 + wm * 128 + i * 16 + quad * 4;
#pragma unroll
        for (int j = 0; j < 4; ++j) {
            const int n = n0 + wn * 64 + j * 16 + l16;
            const float bv = (MODE == 0 || kh == 0) ? be[n] : 0.0f;
#pragma unroll
            for (int r = 0; r < 4; ++r) {
                const int m = mb + r;
                float v = acc[i][j][r] + bv;
                if (MODE == 0) {
                    v = v > 0.0f ? v : 0.0f;
                    outH[(size_t)(off + m) * N + n] = (f16)v;
                } else if (m < cnt) {
                    const int tok = toklist ? toklist[off + m] : m;
                    atomicAdd(&outF[(size_t)tok * N + n], wts[tok * 4 + e] * v);
                }
            }
        }
    }
}

extern "C" void kernel_launch(void* const* d_in, const int* in_sizes, int n_in,
                              void* d_out, int out_size, void* d_ws, size_t ws_size,
                              hipStream_t stream) {
    (void)in_sizes; (void)n_in;
    const float* x  = (const float*)d_in[0];
    const float* Wr = (const float*)d_in[1];
    const float* W1 = (const float*)d_in[2];
    const float* b1 = (const float*)d_in[3];
    const float* W2 = (const float*)d_in[4];
    const float* b2 = (const float*)d_in[5];
    float* out = (float*)d_out;

    char* ws = (char*)d_ws;
    float*  wts   = (float*)ws;                     // [0,128K)
    int*    meta  = (int*)(ws + (128 << 10));       // [128K,132K)
    int*    top2  = (int*)(ws + (132 << 10));       // [132K,164K)
    int*    tokl  = (int*)(ws + (164 << 10));       // [164K,232K) TOTPAD ints
    f16*    xb    = (f16*)(ws + (512 << 10));       // 16 MB
    const size_t MBs = 1ull << 20;
    const size_t base = (512 << 10) + 16 * MBs;

    const size_t SPARSE_NEED = (512 << 10) + 80 * MBs + (size_t)TOTPAD * HDIM * sizeof(f16);
    const bool sparse = ws_size >= SPARSE_NEED;

    f16 *w1t, *w2t, *h;
    if (sparse) {
        w1t = (f16*)(ws + base);             // 32 MB [E] fragment-major B1
        w2t = (f16*)(ws + base + 32 * MBs);  // 32 MB [E] fragment-major B2
        h   = (f16*)(ws + base + 64 * MBs);  // 136 MB (TOTPAD x HDIM)
    } else {
        w1t = (f16*)(ws + base);             // 8 MB, per-expert reuse
        w2t = (f16*)(ws + base + 8 * MBs);   // 8 MB
        h   = (f16*)(ws + base + 16 * MBs);  // 64 MB
    }

    router_kernel<<<M_TOK / 4, 256, 0, stream>>>(x, Wr, wts, top2, xb);
    // out is accumulated into by gemm<1> atomics -> zero it (covers aux slot)
    hipMemsetAsync(out, 0, (size_t)out_size * sizeof(float), stream);

    if (sparse) {
        hipMemsetAsync(meta, 0, 16 * sizeof(int), stream);
        hipMemsetAsync(tokl, 0, (size_t)TOTPAD * sizeof(int), stream);
        count_kernel<<<M_TOK / 256, 256, 0, stream>>>(top2, meta);
        offsets_kernel<<<1, 64, 0, stream>>>(meta);
        fill_kernel<<<M_TOK / 256, 256, 0, stream>>>(top2, meta, tokl);
        // fragment-major weight packs (baseline-verified layout)
        pack_b_kernel<<<dim3(HDIM / 64, DDIM / 64, NEXP), 256, 0, stream>>>(W1, w1t, DDIM, HDIM);
        pack_b_kernel<<<dim3(DDIM / 64, HDIM / 64, NEXP), 256, 0, stream>>>(W2, w2t, HDIM, DDIM);
        const int GX = TOTPAD / 256;  // 68; per-expert blocks gated by cp
        // h = relu(x_gather @ W1 + b1)
        gemm_kernel<0, 1><<<dim3(GX, HDIM / 128, NEXP), 256, 0, stream>>>(
            xb, w1t, HDIM, DDIM, b1, h, nullptr, wts, tokl, meta, 0);
        // out += w * (h @ W2 + b2), split-K=2, fused weighted-atomic epilogue
        gemm_kernel<1, 2><<<dim3(GX, DDIM / 128, NEXP * 2), 256, 0, stream>>>(
            h, w2t, DDIM, HDIM, b2, nullptr, out, wts, tokl, meta, 0);
    } else {
        for (int e = 0; e < NEXP; ++e) {
            pack_b_kernel<<<dim3(HDIM / 64, DDIM / 64, 1), 256, 0, stream>>>(
                W1 + (size_t)e * DDIM * HDIM, w1t, DDIM, HDIM);
            gemm_kernel<0, 1><<<dim3(M_TOK / 256, HDIM / 128, 1), 256, 0, stream>>>(
                xb, w1t, HDIM, DDIM, b1 + (size_t)e * HDIM, h, nullptr, wts, nullptr, nullptr, e);
            pack_b_kernel<<<dim3(DDIM / 64, HDIM / 64, 1), 256, 0, stream>>>(
                W2 + (size_t)e * HDIM * DDIM, w2t, HDIM, DDIM);
            gemm_kernel<1, 1><<<dim3(M_TOK / 256, DDIM / 128, 1), 256, 0, stream>>>(
                h, w2t, DDIM, HDIM, b2 + (size_t)e * DDIM, nullptr, out, wts, nullptr, nullptr, e);
        }
    }
}

// Round 6
// 752.255 us; speedup vs baseline: 1.1703x; 1.1703x over previous
//
#include <hip/hip_runtime.h>
#include <cstdint>
#include <cstddef>

typedef _Float16 f16;
typedef __attribute__((ext_vector_type(8))) f16 f16x8;
typedef __attribute__((ext_vector_type(4))) f16 f16x4;
typedef __attribute__((ext_vector_type(4))) float f32x4;

#define M_TOK 8192
#define DDIM 1024
#define HDIM 4096
#define NEXP 4
#define TOTPAD 16640  // 260*64; >= 16384 + 4*63 (BM=64 padding)

// async global->LDS, 16B per lane (LDS dest = wave-uniform base + lane*16).
__device__ __forceinline__ void async_copy16(const void* g, void* s) {
    __builtin_amdgcn_global_load_lds((__attribute__((address_space(1))) void*)g,
                                     (__attribute__((address_space(3))) void*)s,
                                     16, 0, 0);
}

// inline-asm ds_read_b128 (keeps compiler aliasing model away from in-flight
// global_load_lds; ordering vs MFMA via lgkmcnt(0)+sched_barrier(0), rule #18).
__device__ __forceinline__ f16x8 ds_read_b128_f16(uint32_t addr) {
    f16x8 r;
    asm volatile("ds_read_b128 %0, %1" : "=v"(r) : "v"(addr));
    return r;
}
__device__ __forceinline__ uint32_t lds_addr(const void* p) {
    return (uint32_t)(uintptr_t)(__attribute__((address_space(3))) const void*)p;
}

// ---- Router: logits -> top2 softmax weights; also emits xb (f16) ---------
__global__ __launch_bounds__(256) void router_kernel(
    const float* __restrict__ x, const float* __restrict__ Wr,
    float* __restrict__ wts, int* __restrict__ top2, float2* __restrict__ wpair,
    f16* __restrict__ xb) {
    __shared__ float wr_s[DDIM * NEXP];
    for (int i = threadIdx.x; i < DDIM * NEXP; i += 256) wr_s[i] = Wr[i];
    __syncthreads();
    const int wave = threadIdx.x >> 6, lane = threadIdx.x & 63;
    const int t = blockIdx.x * 4 + wave;
    float a0 = 0.f, a1 = 0.f, a2 = 0.f, a3 = 0.f;
    const float* xr = x + (size_t)t * DDIM;
    f16* xo = xb + (size_t)t * DDIM;
    for (int i = 0; i < DDIM; i += 256) {
        const int d = i + lane * 4;
        const float4 v = *(const float4*)(xr + d);
        f16x4 o = {(f16)v.x, (f16)v.y, (f16)v.z, (f16)v.w};
        *(f16x4*)(xo + d) = o;  // fused fp32->f16 conversion
        const float* w0 = &wr_s[d * 4];
        a0 += v.x * w0[0] + v.y * w0[4] + v.z * w0[8]  + v.w * w0[12];
        a1 += v.x * w0[1] + v.y * w0[5] + v.z * w0[9]  + v.w * w0[13];
        a2 += v.x * w0[2] + v.y * w0[6] + v.z * w0[10] + v.w * w0[14];
        a3 += v.x * w0[3] + v.y * w0[7] + v.z * w0[11] + v.w * w0[15];
    }
    for (int off = 32; off > 0; off >>= 1) {
        a0 += __shfl_xor(a0, off, 64);
        a1 += __shfl_xor(a1, off, 64);
        a2 += __shfl_xor(a2, off, 64);
        a3 += __shfl_xor(a3, off, 64);
    }
    if (lane == 0) {
        float lg[4] = {a0, a1, a2, a3};
        int i1 = 0;
        for (int e = 1; e < 4; ++e) if (lg[e] > lg[i1]) i1 = e;
        int i2 = -1;
        for (int e = 0; e < 4; ++e) {
            if (e == i1) continue;
            if (i2 < 0 || lg[e] > lg[i2]) i2 = e;
        }
        const float w1 = 1.0f / (1.0f + expf(lg[i2] - lg[i1]));
        float w[4] = {0.f, 0.f, 0.f, 0.f};
        w[i1] = w1; w[i2] = 1.0f - w1;
        float* o = wts + (size_t)t * 4;
        o[0] = w[0]; o[1] = w[1]; o[2] = w[2]; o[3] = w[3];
        top2[t] = i1 | (i2 << 8);
        wpair[t] = make_float2(w1, 1.0f - w1);
    }
}

// ---------------- count / fill (sparse routing lists) ---------------------
__global__ __launch_bounds__(256) void count_kernel(
    const int* __restrict__ top2, int* __restrict__ meta) {
    __shared__ int lc[4];
    if (threadIdx.x < 4) lc[threadIdx.x] = 0;
    __syncthreads();
    const int t = blockIdx.x * 256 + threadIdx.x;
    const int p = top2[t];
    atomicAdd(&lc[p & 0xff], 1);
    atomicAdd(&lc[(p >> 8) & 0xff], 1);
    __syncthreads();
    if (threadIdx.x < 4) atomicAdd(&meta[threadIdx.x], lc[threadIdx.x]);
}

// fill also derives cp/offsets locally from the final counts (count_kernel
// already completed) and publishes meta[4..11] (duplicate writes benign) —
// removes the single-block offsets_kernel launch.
__global__ __launch_bounds__(256) void fill_kernel(
    const int* __restrict__ top2, int* __restrict__ meta,
    int* __restrict__ toklist, int2* __restrict__ slotmap) {
    __shared__ int lc[4], base[4], soff[4];
    if (threadIdx.x < 4) lc[threadIdx.x] = 0;
    __syncthreads();
    const int t = blockIdx.x * 256 + threadIdx.x;
    const int p = top2[t];
    const int e1 = p & 0xff, e2 = (p >> 8) & 0xff;
    const int r1 = atomicAdd(&lc[e1], 1);
    const int r2 = atomicAdd(&lc[e2], 1);
    __syncthreads();
    if (threadIdx.x < 4) {
        int offv = 0;
        for (int q = 0; q < threadIdx.x; ++q) offv += (meta[q] + 63) & ~63;
        soff[threadIdx.x] = offv;
        base[threadIdx.x] = atomicAdd(&meta[12 + threadIdx.x], lc[threadIdx.x]);
        meta[4 + threadIdx.x] = (meta[threadIdx.x] + 63) & ~63;  // cp (64-pad)
        meta[8 + threadIdx.x] = offv;                            // segment off
    }
    __syncthreads();
    const int p1 = soff[e1] + base[e1] + r1;
    const int p2 = soff[e2] + base[e2] + r2;
    toklist[p1] = t;
    toklist[p2] = t;
    slotmap[t] = make_int2(p1, p2);
}

// -------- pack W [K][N] fp32 -> plain [N][K] f16 (per z-expert) -----------
__global__ __launch_bounds__(256) void pack_nk_kernel(
    const float* __restrict__ in0, f16* __restrict__ out0, int K, int N) {
    __shared__ float tile[64][65];
    const float* in = in0 + (size_t)blockIdx.z * K * N;
    f16* out = out0 + (size_t)blockIdx.z * K * N;
    const int n0 = blockIdx.x * 64, k0 = blockIdx.y * 64;
    const int tx = threadIdx.x & 63, ty = threadIdx.x >> 6;  // ty 0..3
#pragma unroll
    for (int i = 0; i < 64; i += 4)
        tile[ty + i][tx] = in[(size_t)(k0 + ty + i) * N + n0 + tx];
    __syncthreads();
#pragma unroll
    for (int c = 0; c < 2; ++c) {                 // 512 16B chunks per 64x64 tile
        const int cc = c * 256 + threadIdx.x;     // 0..511
        const int nl = cc >> 3, kc = cc & 7;
        f16x8 v;
#pragma unroll
        for (int j = 0; j < 8; ++j) v[j] = (f16)tile[kc * 8 + j][nl];
        *(f16x8*)&out[(size_t)(n0 + nl) * K + k0 + kc * 8] = v;
    }
}

// ---- 64x128 GEMM, BK=32, 2 waves (wave-tile 64x64), 5 blocks/CU ----------
// LDS 32 KiB (12 KiB used per buf: A 64x32 f16 = 4 KiB @0, B 128x32 f16 =
// 8 KiB @2048 f16; padded to 16 KiB/buf so occupancy is LDS-pinned at
// exactly 5 blocks/CU = 1280 slots -> g0 eff 92%, g1 eff 81%, robust to
// VGPR count).  Five independent 2-wave blocks per CU interleave MFMA with
// LDS-read/stage phases (r4's 2 barrier-locked blocks exposed the reads).
// Schedule/tile t: ph0 {8 ds_reads; bar; lgkm0; 8 MFMA j01; bar},
// ph1 {stage t+2 -> S[p] (reads of S[p] proven complete); 8 MFMA j23;
// vmcnt(6); bar}.  Ledger: 6 loads/tile; wait keeps newest 6 (t+2) in
// flight, guarantees t+1 landed.  Swizzle both-sides: chunk ^= (row>>1)&3
// (same algebra as r4, row stride 64B -> measured 0 conflicts).
template <int MODE>
__global__ __launch_bounds__(128, 3) void gemm_kernel(
    const f16* __restrict__ A, const f16* __restrict__ Bt, int N, int K,
    const float* __restrict__ bias, f16* __restrict__ outH, float* __restrict__ outF,
    const float* __restrict__ wts, const int* __restrict__ toklist,
    const int* __restrict__ meta, int e0) {
    __shared__ __align__(16) f16 S[2][8192];  // 32 KiB
    const int zz = blockIdx.z;
    const int e = e0 + zz;
    const int m0 = blockIdx.x * 64, n0 = blockIdx.y * 128;
    int cnt = M_TOK, cp = M_TOK, off = 0;
    if (meta) { cnt = meta[e]; cp = meta[4 + e]; off = meta[8 + e]; }
    if (m0 >= cp) return;

    const f16* Be = Bt + (size_t)zz * N * K;
    const float* be = bias + (size_t)zz * N;

    const int tid = threadIdx.x;          // 0..127
    const int wn = tid >> 6, lane = tid & 63;
    const int quad = lane >> 4, l16 = lane & 15;
    const int NT = K >> 5;

    // staging sources: A rows r0, 32+r0; B rows r0+{0,32,64,96}; inv-swizzle
    const int r0 = tid >> 2;                              // 0..31
    const int gswz = ((tid & 3) ^ ((r0 >> 1) & 3)) * 8;   // f16 units
    const f16* ga[2]; const f16* gb[4];
#pragma unroll
    for (int g = 0; g < 2; ++g) {
        const int gm = m0 + g * 32 + r0;
        int arow;
        if (MODE == 0) arow = toklist ? toklist[off + gm] : gm;
        else arow = off + gm;
        ga[g] = A + (size_t)arow * K + gswz;
    }
#pragma unroll
    for (int g = 0; g < 4; ++g)
        gb[g] = Be + (size_t)(n0 + g * 32 + r0) * K + gswz;

    const int chq = ((quad ^ ((l16 >> 1) & 3)) << 3);
    const uint32_t sb0 = lds_addr(&S[0][0]), sb1 = lds_addr(&S[1][0]);
    const uint32_t a_b = (uint32_t)((l16 * 32 + chq) * 2);
    const uint32_t b_b = (uint32_t)((2048 + (wn * 64 + l16) * 32 + chq) * 2);

    f32x4 acc[4][4] = {};

#define STAGE6(koff, buf)                                   \
    do {                                                    \
        async_copy16(ga[0] + (koff), (buf) + tid * 8);          \
        async_copy16(ga[1] + (koff), (buf) + 1024 + tid * 8);   \
        async_copy16(gb[0] + (koff), (buf) + 2048 + tid * 8);   \
        async_copy16(gb[1] + (koff), (buf) + 3072 + tid * 8);   \
        async_copy16(gb[2] + (koff), (buf) + 4096 + tid * 8);   \
        async_copy16(gb[3] + (koff), (buf) + 5120 + tid * 8);   \
    } while (0)

    // prologue: tile0 -> S0, tile1 -> S1
    STAGE6(0, S[0]);
    if (NT > 1) {
        STAGE6(32, S[1]);
        asm volatile("s_waitcnt vmcnt(6)" ::: "memory");  // tile0 landed
    } else {
        asm volatile("s_waitcnt vmcnt(0)" ::: "memory");
    }
    __builtin_amdgcn_s_barrier();

    int p = 0;
#pragma unroll 1
    for (int t = 0; t < NT; ++t) {
        const uint32_t sp = p ? sb1 : sb0;
        f16* SpW = S[p];
        f16x8 af[4], bf[4];
        // ---- phase 0: all 8 fragment reads; MFMA j={0,1}
#pragma unroll
        for (int i = 0; i < 4; ++i) af[i] = ds_read_b128_f16(sp + a_b + i * 1024);
#pragma unroll
        for (int j = 0; j < 4; ++j) bf[j] = ds_read_b128_f16(sp + b_b + j * 1024);
        __builtin_amdgcn_s_barrier();
        asm volatile("s_waitcnt lgkmcnt(0)" ::: "memory");
        __builtin_amdgcn_sched_barrier(0);
        __builtin_amdgcn_s_setprio(1);
#pragma unroll
        for (int i = 0; i < 4; ++i) {
            acc[i][0] = __builtin_amdgcn_mfma_f32_16x16x32_f16(af[i], bf[0], acc[i][0], 0, 0, 0);
            acc[i][1] = __builtin_amdgcn_mfma_f32_16x16x32_f16(af[i], bf[1], acc[i][1], 0, 0, 0);
        }
        __builtin_amdgcn_s_setprio(0);
        __builtin_amdgcn_s_barrier();
        // ---- phase 1: stage t+2 into this buf (all reads of S[p] complete:
        //      every wave passed lgkmcnt(0) before the barrier above);
        //      MFMA j={2,3} from registers; counted drain
        if (t + 2 < NT) STAGE6((t + 2) << 5, SpW);
        __builtin_amdgcn_s_setprio(1);
#pragma unroll
        for (int i = 0; i < 4; ++i) {
            acc[i][2] = __builtin_amdgcn_mfma_f32_16x16x32_f16(af[i], bf[2], acc[i][2], 0, 0, 0);
            acc[i][3] = __builtin_amdgcn_mfma_f32_16x16x32_f16(af[i], bf[3], acc[i][3], 0, 0, 0);
        }
        __builtin_amdgcn_s_setprio(0);
        if (t + 2 < NT) asm volatile("s_waitcnt vmcnt(6)" ::: "memory");
        else            asm volatile("s_waitcnt vmcnt(0)" ::: "memory");
        __builtin_amdgcn_s_barrier();
        p ^= 1;
    }
#undef STAGE6

    // epilogue: C/D layout col = lane&15, row = quad*4 + reg
#pragma unroll
    for (int i = 0; i < 4; ++i) {
        const int mb = m0 + i * 16 + quad * 4;
#pragma unroll
        for (int j = 0; j < 4; ++j) {
            const int n = n0 + wn * 64 + j * 16 + l16;
            const float bv = be[n];
#pragma unroll
            for (int r = 0; r < 4; ++r) {
                const int m = mb + r;
                float v = acc[i][j][r] + bv;
                if (MODE == 0) {
                    v = v > 0.0f ? v : 0.0f;
                    outH[(size_t)(off + m) * N + n] = (f16)v;
                } else {
                    if (outH) {  // sparse: f16 segment write (padded rows ok)
                        outH[(size_t)(off + m) * N + n] = (f16)v;
                    } else if (m < cnt) {  // dense fallback: weighted atomic
                        atomicAdd(&outF[(size_t)m * N + n], wts[m * 4 + e] * v);
                    }
                }
            }
        }
    }
}

// ---------------- combine: out[t] = w1*yseg[p1] + w2*yseg[p2] --------------
__global__ __launch_bounds__(256) void combine_kernel(
    const f16* __restrict__ yseg, const int2* __restrict__ slotmap,
    const float2* __restrict__ wpair, float* __restrict__ out, int aux_idx) {
    const int t = blockIdx.x;
    const int2 p = slotmap[t];
    const float2 w = wpair[t];
    const int d = threadIdx.x * 4;
    const f16x4 a = *(const f16x4*)&yseg[(size_t)p.x * DDIM + d];
    const f16x4 b = *(const f16x4*)&yseg[(size_t)p.y * DDIM + d];
    float4 o;
    o.x = w.x * (float)a[0] + w.y * (float)b[0];
    o.y = w.x * (float)a[1] + w.y * (float)b[1];
    o.z = w.x * (float)a[2] + w.y * (float)b[2];
    o.w = w.x * (float)a[3] + w.y * (float)b[3];
    *(float4*)&out[(size_t)t * DDIM + d] = o;
    if (t == 0 && threadIdx.x == 0 && aux_idx >= 0) out[aux_idx] = 0.0f;
}

extern "C" void kernel_launch(void* const* d_in, const int* in_sizes, int n_in,
                              void* d_out, int out_size, void* d_ws, size_t ws_size,
                              hipStream_t stream) {
    (void)in_sizes; (void)n_in;
    const float* x  = (const float*)d_in[0];
    const float* Wr = (const float*)d_in[1];
    const float* W1 = (const float*)d_in[2];
    const float* b1 = (const float*)d_in[3];
    const float* W2 = (const float*)d_in[4];
    const float* b2 = (const float*)d_in[5];
    float* out = (float*)d_out;

    char* ws = (char*)d_ws;
    float*  wts   = (float*)ws;                     // [0,128K)
    int*    meta  = (int*)(ws + (128 << 10));       // [128K,132K)
    int*    top2  = (int*)(ws + (132 << 10));       // [132K,164K)
    int*    tokl  = (int*)(ws + (164 << 10));       // [164K,232K) TOTPAD ints
    float2* wpair = (float2*)(ws + (240 << 10));    // [240K,304K)
    int2*   slotm = (int2*)(ws + (304 << 10));      // [304K,368K)
    f16*    xb    = (f16*)(ws + (512 << 10));       // 16 MB
    const size_t MBs = 1ull << 20;
    const size_t base = (512 << 10) + 16 * MBs;

    const size_t SPARSE_NEED = (512 << 10) + 80 * MBs + (size_t)TOTPAD * HDIM * sizeof(f16);
    const bool sparse = ws_size >= SPARSE_NEED;

    const int aux_idx = (out_size == M_TOK * DDIM + 1) ? (M_TOK * DDIM) : -1;

    f16 *w1t, *w2t, *h, *yseg;
    if (sparse) {
        w1t  = (f16*)(ws + base);             // 32 MB [E] plain [N][K]
        w2t  = (f16*)(ws + base + 32 * MBs);  // 32 MB [E] plain [N][K]
        h    = (f16*)(ws + base + 64 * MBs);  // 130 MB (TOTPAD x HDIM)
        yseg = (f16*)(ws + (512 << 10));      // 32.5 MB overlay on xb+w1t
                                              // (both dead before gemm<1> runs)
    } else {
        w1t = (f16*)(ws + base);             // 8 MB, per-expert reuse
        w2t = (f16*)(ws + base + 8 * MBs);   // 8 MB
        h   = (f16*)(ws + base + 16 * MBs);  // 64 MB
        yseg = nullptr;
    }

    router_kernel<<<M_TOK / 4, 256, 0, stream>>>(x, Wr, wts, top2, wpair, xb);

    if (sparse) {
        hipMemsetAsync(meta, 0, 16 * sizeof(int), stream);
        hipMemsetAsync(tokl, 0, (size_t)TOTPAD * sizeof(int), stream);
        count_kernel<<<M_TOK / 256, 256, 0, stream>>>(top2, meta);
        fill_kernel<<<M_TOK / 256, 256, 0, stream>>>(top2, meta, tokl, slotm);
        // plain [N][K] weight packs
        pack_nk_kernel<<<dim3(HDIM / 64, DDIM / 64, NEXP), 256, 0, stream>>>(W1, w1t, DDIM, HDIM);
        pack_nk_kernel<<<dim3(DDIM / 64, HDIM / 64, NEXP), 256, 0, stream>>>(W2, w2t, HDIM, DDIM);
        const int GX = TOTPAD / 64;  // 260; per-expert blocks gated by cp
        // h = relu(x_gather @ W1 + b1), per-expert packed segments
        gemm_kernel<0><<<dim3(GX, HDIM / 128, NEXP), 128, 0, stream>>>(
            xb, w1t, HDIM, DDIM, b1, h, nullptr, wts, tokl, meta, 0);
        // yseg = h @ W2 + b2 (f16 segments; yseg overlays xb/w1t — both dead)
        gemm_kernel<1><<<dim3(GX, DDIM / 128, NEXP), 128, 0, stream>>>(
            h, w2t, DDIM, HDIM, b2, yseg, nullptr, wts, nullptr, meta, 0);
        combine_kernel<<<M_TOK, 256, 0, stream>>>(yseg, slotm, wpair, out, aux_idx);
    } else {
        hipMemsetAsync(out, 0, (size_t)out_size * sizeof(float), stream);
        for (int e = 0; e < NEXP; ++e) {
            pack_nk_kernel<<<dim3(HDIM / 64, DDIM / 64, 1), 256, 0, stream>>>(
                W1 + (size_t)e * DDIM * HDIM, w1t, DDIM, HDIM);
            gemm_kernel<0><<<dim3(M_TOK / 64, HDIM / 128, 1), 128, 0, stream>>>(
                xb, w1t, HDIM, DDIM, b1 + (size_t)e * HDIM, h, nullptr, wts, nullptr, nullptr, e);
            pack_nk_kernel<<<dim3(DDIM / 64, HDIM / 64, 1), 256, 0, stream>>>(
                W2 + (size_t)e * HDIM * DDIM, w2t, HDIM, DDIM);
            gemm_kernel<1><<<dim3(M_TOK / 64, DDIM / 128, 1), 128, 0, stream>>>(
                h, w2t, DDIM, HDIM, b2 + (size_t)e * DDIM, nullptr, out, wts, nullptr, nullptr, e);
        }
    }
}

// Round 7
// 607.103 us; speedup vs baseline: 1.4501x; 1.2391x over previous
//
#include <hip/hip_runtime.h>
#include <cstdint>
#include <cstddef>

typedef _Float16 f16;
typedef __attribute__((ext_vector_type(8))) f16 f16x8;
typedef __attribute__((ext_vector_type(4))) f16 f16x4;
typedef __attribute__((ext_vector_type(4))) float f32x4;

#define M_TOK 8192
#define DDIM 1024
#define HDIM 4096
#define NEXP 4
#define TOTPAD 17408  // >= 16384 + 4*255, 256-pad (gemm256 BM); 128 divides too

// async global->LDS, 16B per lane (LDS dest = wave-uniform base + lane*16).
__device__ __forceinline__ void async_copy16(const void* g, void* s) {
    __builtin_amdgcn_global_load_lds((__attribute__((address_space(1))) void*)g,
                                     (__attribute__((address_space(3))) void*)s,
                                     16, 0, 0);
}

// inline-asm ds_read_b128 (keeps compiler aliasing model away from in-flight
// global_load_lds; ordering vs MFMA via lgkmcnt(0)+sched_barrier(0), rule #18).
__device__ __forceinline__ f16x8 ds_read_b128_f16(uint32_t addr) {
    f16x8 r;
    asm volatile("ds_read_b128 %0, %1" : "=v"(r) : "v"(addr));
    return r;
}
__device__ __forceinline__ uint32_t lds_addr(const void* p) {
    return (uint32_t)(uintptr_t)(__attribute__((address_space(3))) const void*)p;
}

// stage one 16-KiB k-plane (256 rows x 32 f16), 512 threads, 2 loads/thread.
__device__ __forceinline__ void stageP512(const f16* g0, const f16* g1, int koff,
                                          f16* plane, int tid) {
    async_copy16(g0 + koff, plane + tid * 8);
    async_copy16(g1 + koff, plane + 4096 + tid * 8);
}
// stage one 8-KiB k-plane (128 rows x 32 f16), 256 threads, 2 loads/thread.
__device__ __forceinline__ void stageP256(const f16* g0, const f16* g1, int koff,
                                          f16* plane, int tid) {
    async_copy16(g0 + koff, plane + tid * 8);
    async_copy16(g1 + koff, plane + 2048 + tid * 8);
}

// ---- Router: logits -> top2 softmax weights; also emits xb (f16) ---------
__global__ __launch_bounds__(256) void router_kernel(
    const float* __restrict__ x, const float* __restrict__ Wr,
    float* __restrict__ wts, int* __restrict__ top2, float2* __restrict__ wpair,
    f16* __restrict__ xb) {
    __shared__ float wr_s[DDIM * NEXP];
    for (int i = threadIdx.x; i < DDIM * NEXP; i += 256) wr_s[i] = Wr[i];
    __syncthreads();
    const int wave = threadIdx.x >> 6, lane = threadIdx.x & 63;
    const int t = blockIdx.x * 4 + wave;
    float a0 = 0.f, a1 = 0.f, a2 = 0.f, a3 = 0.f;
    const float* xr = x + (size_t)t * DDIM;
    f16* xo = xb + (size_t)t * DDIM;
    for (int i = 0; i < DDIM; i += 256) {
        const int d = i + lane * 4;
        const float4 v = *(const float4*)(xr + d);
        f16x4 o = {(f16)v.x, (f16)v.y, (f16)v.z, (f16)v.w};
        *(f16x4*)(xo + d) = o;  // fused fp32->f16 conversion
        const float* w0 = &wr_s[d * 4];
        a0 += v.x * w0[0] + v.y * w0[4] + v.z * w0[8]  + v.w * w0[12];
        a1 += v.x * w0[1] + v.y * w0[5] + v.z * w0[9]  + v.w * w0[13];
        a2 += v.x * w0[2] + v.y * w0[6] + v.z * w0[10] + v.w * w0[14];
        a3 += v.x * w0[3] + v.y * w0[7] + v.z * w0[11] + v.w * w0[15];
    }
    for (int off = 32; off > 0; off >>= 1) {
        a0 += __shfl_xor(a0, off, 64);
        a1 += __shfl_xor(a1, off, 64);
        a2 += __shfl_xor(a2, off, 64);
        a3 += __shfl_xor(a3, off, 64);
    }
    if (lane == 0) {
        float lg[4] = {a0, a1, a2, a3};
        int i1 = 0;
        for (int e = 1; e < 4; ++e) if (lg[e] > lg[i1]) i1 = e;
        int i2 = -1;
        for (int e = 0; e < 4; ++e) {
            if (e == i1) continue;
            if (i2 < 0 || lg[e] > lg[i2]) i2 = e;
        }
        const float w1 = 1.0f / (1.0f + expf(lg[i2] - lg[i1]));
        float w[4] = {0.f, 0.f, 0.f, 0.f};
        w[i1] = w1; w[i2] = 1.0f - w1;
        float* o = wts + (size_t)t * 4;
        o[0] = w[0]; o[1] = w[1]; o[2] = w[2]; o[3] = w[3];
        top2[t] = i1 | (i2 << 8);
        wpair[t] = make_float2(w1, 1.0f - w1);
    }
}

// ---------------- count / fill (sparse routing lists) ---------------------
__global__ __launch_bounds__(256) void count_kernel(
    const int* __restrict__ top2, int* __restrict__ meta) {
    __shared__ int lc[4];
    if (threadIdx.x < 4) lc[threadIdx.x] = 0;
    __syncthreads();
    const int t = blockIdx.x * 256 + threadIdx.x;
    const int p = top2[t];
    atomicAdd(&lc[p & 0xff], 1);
    atomicAdd(&lc[(p >> 8) & 0xff], 1);
    __syncthreads();
    if (threadIdx.x < 4) atomicAdd(&meta[threadIdx.x], lc[threadIdx.x]);
}

// fill derives cp/offsets locally from final counts (count_kernel complete)
// and publishes meta[4..11] (duplicate writes benign) — no offsets launch.
__global__ __launch_bounds__(256) void fill_kernel(
    const int* __restrict__ top2, int* __restrict__ meta,
    int* __restrict__ toklist, int2* __restrict__ slotmap) {
    __shared__ int lc[4], base[4], soff[4];
    if (threadIdx.x < 4) lc[threadIdx.x] = 0;
    __syncthreads();
    const int t = blockIdx.x * 256 + threadIdx.x;
    const int p = top2[t];
    const int e1 = p & 0xff, e2 = (p >> 8) & 0xff;
    const int r1 = atomicAdd(&lc[e1], 1);
    const int r2 = atomicAdd(&lc[e2], 1);
    __syncthreads();
    if (threadIdx.x < 4) {
        int offv = 0;
        for (int q = 0; q < threadIdx.x; ++q) offv += (meta[q] + 255) & ~255;
        soff[threadIdx.x] = offv;
        base[threadIdx.x] = atomicAdd(&meta[12 + threadIdx.x], lc[threadIdx.x]);
        meta[4 + threadIdx.x] = (meta[threadIdx.x] + 255) & ~255;  // cp 256-pad
        meta[8 + threadIdx.x] = offv;                              // segment off
    }
    __syncthreads();
    const int p1 = soff[e1] + base[e1] + r1;
    const int p2 = soff[e2] + base[e2] + r2;
    toklist[p1] = t;
    toklist[p2] = t;
    slotmap[t] = make_int2(p1, p2);
}

// -------- pack W [K][N] fp32 -> plain [N][K] f16 (per z-expert) -----------
__global__ __launch_bounds__(256) void pack_nk_kernel(
    const float* __restrict__ in0, f16* __restrict__ out0, int K, int N) {
    __shared__ float tile[64][65];
    const float* in = in0 + (size_t)blockIdx.z * K * N;
    f16* out = out0 + (size_t)blockIdx.z * K * N;
    const int n0 = blockIdx.x * 64, k0 = blockIdx.y * 64;
    const int tx = threadIdx.x & 63, ty = threadIdx.x >> 6;  // ty 0..3
#pragma unroll
    for (int i = 0; i < 64; i += 4)
        tile[ty + i][tx] = in[(size_t)(k0 + ty + i) * N + n0 + tx];
    __syncthreads();
#pragma unroll
    for (int c = 0; c < 2; ++c) {                 // 512 16B chunks per 64x64 tile
        const int cc = c * 256 + threadIdx.x;     // 0..511
        const int nl = cc >> 3, kc = cc & 7;
        f16x8 v;
#pragma unroll
        for (int j = 0; j < 8; ++j) v[j] = (f16)tile[kc * 8 + j][nl];
        *(f16x8*)&out[(size_t)(n0 + nl) * K + k0 + kc * 8] = v;
    }
}

// ---- 256x256 GEMM, BK=64, 8 waves, 4-phase counted-vmcnt (r1/r2-verified) -
// Used for MODE 0 (g0: 1056 active blocks -> ~82% busy; per-CU ~47% — the
// 256^2 tile has 22.9 B/KFLOP LDS traffic vs 128^2's 38, ceiling 83% vs 50%).
template <int MODE>
__global__ __launch_bounds__(512, 2) void gemm256_kernel(
    const f16* __restrict__ A, const f16* __restrict__ Bt, int N, int K,
    const float* __restrict__ bias, f16* __restrict__ outH, float* __restrict__ outF,
    const float* __restrict__ wts, const int* __restrict__ toklist,
    const int* __restrict__ meta, int e0) {
    __shared__ __align__(16) f16 S[2][32768];  // 128 KiB
    const int zz = blockIdx.z;
    const int e = e0 + zz;
    const int m0 = blockIdx.x * 256, n0 = blockIdx.y * 256;
    int cnt = M_TOK, cp = M_TOK, off = 0;
    if (meta) { cnt = meta[e]; cp = meta[4 + e]; off = meta[8 + e]; }
    if (m0 >= cp) return;
    (void)cnt;

    const f16* Be = Bt + (size_t)zz * N * K;
    const float* be = bias + (size_t)zz * N;

    const int tid = threadIdx.x;
    const int wave = tid >> 6, lane = tid & 63;
    const int wm = wave >> 2, wn = wave & 3;      // 2M x 4N waves
    const int quad = lane >> 4, l16 = lane & 15;
    const int NT = K >> 6;

    const int r0 = tid >> 2;
    const int gswz = ((tid & 3) ^ ((r0 >> 1) & 3)) * 8;  // f16 units
    const f16* ga[2]; const f16* gb[2];
#pragma unroll
    for (int q = 0; q < 2; ++q) {
        const int gm = m0 + q * 128 + r0;
        int arow;
        if (MODE == 0) arow = toklist ? toklist[off + gm] : gm;
        else arow = off + gm;
        ga[q] = A + (size_t)arow * K + gswz;
        gb[q] = Be + (size_t)(n0 + q * 128 + r0) * K + gswz;
    }

    const int chq = ((quad ^ ((l16 >> 1) & 3)) << 3);
    const uint32_t sb0 = lds_addr(&S[0][0]), sb1 = lds_addr(&S[1][0]);
    const uint32_t a_b = (uint32_t)(((wm * 128 + l16) * 32 + chq) * 2);
    const uint32_t b_b = (uint32_t)((16384 + (wn * 64 + l16) * 32 + chq) * 2);

    f32x4 acc[8][4] = {};

    // prologue: tile0 (4 planes) -> S[0]; tile1 (3 planes) -> S[1]
    stageP512(ga[0], ga[1], 0,  S[0] + 0,     tid);   // A_k0(0)
    stageP512(gb[0], gb[1], 0,  S[0] + 16384, tid);   // B_k0(0)
    stageP512(ga[0], ga[1], 32, S[0] + 8192,  tid);   // A_k1(0)
    stageP512(gb[0], gb[1], 32, S[0] + 24576, tid);   // B_k1(0)
    if (NT > 1) {
        stageP512(ga[0], ga[1], 64, S[1] + 0,     tid);   // A_k0(1)
        stageP512(gb[0], gb[1], 64, S[1] + 16384, tid);   // B_k0(1)
        stageP512(ga[0], ga[1], 96, S[1] + 8192,  tid);   // A_k1(1)
        asm volatile("s_waitcnt vmcnt(6)" ::: "memory");
    } else {
        asm volatile("s_waitcnt vmcnt(0)" ::: "memory");
    }
    __builtin_amdgcn_s_barrier();

    int p = 0;
#pragma unroll 1
    for (int t = 0; t < NT; ++t) {
        const uint32_t sp = p ? sb1 : sb0;
        f16* SpW = S[p];
        f16* SoW = S[p ^ 1];
        f16x8 af[8], bf0, bf1;
        // ---- phase 0: kk2=0, j={0,1}; stage B_k1(t+1) -> other buf
#pragma unroll
        for (int i = 0; i < 8; ++i) af[i] = ds_read_b128_f16(sp + a_b + i * 1024);
        bf0 = ds_read_b128_f16(sp + b_b);
        bf1 = ds_read_b128_f16(sp + b_b + 1024);
        if (t + 1 < NT) stageP512(gb[0], gb[1], ((t + 1) << 6) + 32, SoW + 24576, tid);
        __builtin_amdgcn_s_barrier();
        asm volatile("s_waitcnt lgkmcnt(0)" ::: "memory");
        __builtin_amdgcn_sched_barrier(0);
        __builtin_amdgcn_s_setprio(1);
#pragma unroll
        for (int i = 0; i < 8; ++i) {
            acc[i][0] = __builtin_amdgcn_mfma_f32_16x16x32_f16(af[i], bf0, acc[i][0], 0, 0, 0);
            acc[i][1] = __builtin_amdgcn_mfma_f32_16x16x32_f16(af[i], bf1, acc[i][1], 0, 0, 0);
        }
        __builtin_amdgcn_s_setprio(0);
        __builtin_amdgcn_s_barrier();
        // ---- phase 1: kk2=0, j={2,3}; stage A_k0(t+2) -> this buf
        bf0 = ds_read_b128_f16(sp + b_b + 2048);
        bf1 = ds_read_b128_f16(sp + b_b + 3072);
        if (t + 2 < NT) stageP512(ga[0], ga[1], (t + 2) << 6, SpW, tid);
        __builtin_amdgcn_s_barrier();
        asm volatile("s_waitcnt lgkmcnt(0)" ::: "memory");
        __builtin_amdgcn_sched_barrier(0);
        __builtin_amdgcn_s_setprio(1);
#pragma unroll
        for (int i = 0; i < 8; ++i) {
            acc[i][2] = __builtin_amdgcn_mfma_f32_16x16x32_f16(af[i], bf0, acc[i][2], 0, 0, 0);
            acc[i][3] = __builtin_amdgcn_mfma_f32_16x16x32_f16(af[i], bf1, acc[i][3], 0, 0, 0);
        }
        __builtin_amdgcn_s_setprio(0);
        __builtin_amdgcn_s_barrier();
        // ---- phase 2: kk2=1, j={0,1}; stage B_k0(t+2) -> this buf
#pragma unroll
        for (int i = 0; i < 8; ++i)
            af[i] = ds_read_b128_f16(sp + a_b + 16384 + i * 1024);
        bf0 = ds_read_b128_f16(sp + b_b + 16384);
        bf1 = ds_read_b128_f16(sp + b_b + 16384 + 1024);
        if (t + 2 < NT) stageP512(gb[0], gb[1], (t + 2) << 6, SpW + 16384, tid);
        __builtin_amdgcn_s_barrier();
        asm volatile("s_waitcnt lgkmcnt(0)" ::: "memory");
        __builtin_amdgcn_sched_barrier(0);
        __builtin_amdgcn_s_setprio(1);
#pragma unroll
        for (int i = 0; i < 8; ++i) {
            acc[i][0] = __builtin_amdgcn_mfma_f32_16x16x32_f16(af[i], bf0, acc[i][0], 0, 0, 0);
            acc[i][1] = __builtin_amdgcn_mfma_f32_16x16x32_f16(af[i], bf1, acc[i][1], 0, 0, 0);
        }
        __builtin_amdgcn_s_setprio(0);
        __builtin_amdgcn_s_barrier();
        // ---- phase 3: kk2=1, j={2,3}; stage A_k1(t+2); counted vmcnt
        bf0 = ds_read_b128_f16(sp + b_b + 16384 + 2048);
        bf1 = ds_read_b128_f16(sp + b_b + 16384 + 3072);
        if (t + 2 < NT) stageP512(ga[0], ga[1], ((t + 2) << 6) + 32, SpW + 8192, tid);
        __builtin_amdgcn_s_barrier();
        asm volatile("s_waitcnt lgkmcnt(0)" ::: "memory");
        __builtin_amdgcn_sched_barrier(0);
        __builtin_amdgcn_s_setprio(1);
#pragma unroll
        for (int i = 0; i < 8; ++i) {
            acc[i][2] = __builtin_amdgcn_mfma_f32_16x16x32_f16(af[i], bf0, acc[i][2], 0, 0, 0);
            acc[i][3] = __builtin_amdgcn_mfma_f32_16x16x32_f16(af[i], bf1, acc[i][3], 0, 0, 0);
        }
        __builtin_amdgcn_s_setprio(0);
        if (t + 2 < NT) asm volatile("s_waitcnt vmcnt(6)" ::: "memory");
        else            asm volatile("s_waitcnt vmcnt(0)" ::: "memory");
        __builtin_amdgcn_s_barrier();
        p ^= 1;
    }

    // epilogue
#pragma unroll
    for (int i = 0; i < 8; ++i) {
        const int mb = m0 + wm * 128 + i * 16 + quad * 4;
#pragma unroll
        for (int j = 0; j < 4; ++j) {
            const int n = n0 + wn * 64 + j * 16 + l16;
            const float bv = be[n];
#pragma unroll
            for (int r = 0; r < 4; ++r) {
                const int m = mb + r;
                float v = acc[i][j][r] + bv;
                v = v > 0.0f ? v : 0.0f;  // MODE 0 only (relu)
                outH[(size_t)(off + m) * N + n] = (f16)v;
            }
        }
    }
}

// ---- 128x128 GEMM, BK=64, 4 waves, 2 blocks/CU (r4-verified) -------------
template <int MODE>
__global__ __launch_bounds__(256, 2) void gemm128_kernel(
    const f16* __restrict__ A, const f16* __restrict__ Bt, int N, int K,
    const float* __restrict__ bias, f16* __restrict__ outH, float* __restrict__ outF,
    const float* __restrict__ wts, const int* __restrict__ toklist,
    const int* __restrict__ meta, int e0) {
    __shared__ __align__(16) f16 S[2][16384];  // 64 KiB
    const int zz = blockIdx.z;
    const int e = e0 + zz;
    const int m0 = blockIdx.x * 128, n0 = blockIdx.y * 128;
    int cnt = M_TOK, cp = M_TOK, off = 0;
    if (meta) { cnt = meta[e]; cp = meta[4 + e]; off = meta[8 + e]; }
    if (m0 >= cp) return;

    const f16* Be = Bt + (size_t)zz * N * K;
    const float* be = bias + (size_t)zz * N;

    const int tid = threadIdx.x;
    const int wave = tid >> 6, lane = tid & 63;
    const int wm = wave >> 1, wn = wave & 1;      // 2M x 2N waves, 64x64 each
    const int quad = lane >> 4, l16 = lane & 15;
    const int NT = K >> 6;

    const int r0 = tid >> 2;                              // 0..63
    const int gswz = ((tid & 3) ^ ((r0 >> 1) & 3)) * 8;   // f16 units
    const f16* ga[2]; const f16* gb[2];
#pragma unroll
    for (int q = 0; q < 2; ++q) {
        const int gm = m0 + q * 64 + r0;
        int arow;
        if (MODE == 0) arow = toklist ? toklist[off + gm] : gm;
        else arow = off + gm;
        ga[q] = A + (size_t)arow * K + gswz;
        gb[q] = Be + (size_t)(n0 + q * 64 + r0) * K + gswz;
    }

    const int chq = ((quad ^ ((l16 >> 1) & 3)) << 3);
    const uint32_t sb0 = lds_addr(&S[0][0]), sb1 = lds_addr(&S[1][0]);
    const uint32_t a_b = (uint32_t)(((wm * 64 + l16) * 32 + chq) * 2);
    const uint32_t b_b = (uint32_t)((8192 + (wn * 64 + l16) * 32 + chq) * 2);

    f32x4 acc[4][4] = {};

    // prologue: tile0 (4 planes) -> S[0]; tile1 (3 planes) -> S[1]
    stageP256(ga[0], ga[1], 0,  S[0] + 0,     tid);   // A_k0(0)
    stageP256(gb[0], gb[1], 0,  S[0] + 8192,  tid);   // B_k0(0)
    stageP256(ga[0], ga[1], 32, S[0] + 4096,  tid);   // A_k1(0)
    stageP256(gb[0], gb[1], 32, S[0] + 12288, tid);   // B_k1(0)
    if (NT > 1) {
        stageP256(ga[0], ga[1], 64, S[1] + 0,     tid);   // A_k0(1)
        stageP256(gb[0], gb[1], 64, S[1] + 8192,  tid);   // B_k0(1)
        stageP256(ga[0], ga[1], 96, S[1] + 4096,  tid);   // A_k1(1)
        asm volatile("s_waitcnt vmcnt(6)" ::: "memory");
    } else {
        asm volatile("s_waitcnt vmcnt(0)" ::: "memory");
    }
    __builtin_amdgcn_s_barrier();

    int p = 0;
#pragma unroll 1
    for (int t = 0; t < NT; ++t) {
        const uint32_t sp = p ? sb1 : sb0;
        f16* SpW = S[p];
        f16* SoW = S[p ^ 1];
        f16x8 af[4], bf0, bf1;
        // ---- phase 0: kk2=0, j={0,1}; stage B_k1(t+1) -> other buf
#pragma unroll
        for (int i = 0; i < 4; ++i) af[i] = ds_read_b128_f16(sp + a_b + i * 1024);
        bf0 = ds_read_b128_f16(sp + b_b);
        bf1 = ds_read_b128_f16(sp + b_b + 1024);
        if (t + 1 < NT) stageP256(gb[0], gb[1], ((t + 1) << 6) + 32, SoW + 12288, tid);
        __builtin_amdgcn_s_barrier();
        asm volatile("s_waitcnt lgkmcnt(0)" ::: "memory");
        __builtin_amdgcn_sched_barrier(0);
        __builtin_amdgcn_s_setprio(1);
#pragma unroll
        for (int i = 0; i < 4; ++i) {
            acc[i][0] = __builtin_amdgcn_mfma_f32_16x16x32_f16(af[i], bf0, acc[i][0], 0, 0, 0);
            acc[i][1] = __builtin_amdgcn_mfma_f32_16x16x32_f16(af[i], bf1, acc[i][1], 0, 0, 0);
        }
        __builtin_amdgcn_s_setprio(0);
        __builtin_amdgcn_s_barrier();
        // ---- phase 1: kk2=0, j={2,3}; stage A_k0(t+2) -> this buf
        bf0 = ds_read_b128_f16(sp + b_b + 2048);
        bf1 = ds_read_b128_f16(sp + b_b + 3072);
        if (t + 2 < NT) stageP256(ga[0], ga[1], (t + 2) << 6, SpW, tid);
        __builtin_amdgcn_s_barrier();
        asm volatile("s_waitcnt lgkmcnt(0)" ::: "memory");
        __builtin_amdgcn_sched_barrier(0);
        __builtin_amdgcn_s_setprio(1);
#pragma unroll
        for (int i = 0; i < 4; ++i) {
            acc[i][2] = __builtin_amdgcn_mfma_f32_16x16x32_f16(af[i], bf0, acc[i][2], 0, 0, 0);
            acc[i][3] = __builtin_amdgcn_mfma_f32_16x16x32_f16(af[i], bf1, acc[i][3], 0, 0, 0);
        }
        __builtin_amdgcn_s_setprio(0);
        __builtin_amdgcn_s_barrier();
        // ---- phase 2: kk2=1, j={0,1}; stage B_k0(t+2) -> this buf
#pragma unroll
        for (int i = 0; i < 4; ++i)
            af[i] = ds_read_b128_f16(sp + a_b + 8192 + i * 1024);
        bf0 = ds_read_b128_f16(sp + b_b + 8192);
        bf1 = ds_read_b128_f16(sp + b_b + 8192 + 1024);
        if (t + 2 < NT) stageP256(gb[0], gb[1], (t + 2) << 6, SpW + 8192, tid);
        __builtin_amdgcn_s_barrier();
        asm volatile("s_waitcnt lgkmcnt(0)" ::: "memory");
        __builtin_amdgcn_sched_barrier(0);
        __builtin_amdgcn_s_setprio(1);
#pragma unroll
        for (int i = 0; i < 4; ++i) {
            acc[i][0] = __builtin_amdgcn_mfma_f32_16x16x32_f16(af[i], bf0, acc[i][0], 0, 0, 0);
            acc[i][1] = __builtin_amdgcn_mfma_f32_16x16x32_f16(af[i], bf1, acc[i][1], 0, 0, 0);
        }
        __builtin_amdgcn_s_setprio(0);
        __builtin_amdgcn_s_barrier();
        // ---- phase 3: kk2=1, j={2,3}; stage A_k1(t+2); counted vmcnt
        bf0 = ds_read_b128_f16(sp + b_b + 8192 + 2048);
        bf1 = ds_read_b128_f16(sp + b_b + 8192 + 3072);
        if (t + 2 < NT) stageP256(ga[0], ga[1], ((t + 2) << 6) + 32, SpW + 4096, tid);
        __builtin_amdgcn_s_barrier();
        asm volatile("s_waitcnt lgkmcnt(0)" ::: "memory");
        __builtin_amdgcn_sched_barrier(0);
        __builtin_amdgcn_s_setprio(1);
#pragma unroll
        for (int i = 0; i < 4; ++i) {
            acc[i][2] = __builtin_amdgcn_mfma_f32_16x16x32_f16(af[i], bf0, acc[i][2], 0, 0, 0);
            acc[i][3] = __builtin_amdgcn_mfma_f32_16x16x32_f16(af[i], bf1, acc[i][3], 0, 0, 0);
        }
        __builtin_amdgcn_s_setprio(0);
        if (t + 2 < NT) asm volatile("s_waitcnt vmcnt(6)" ::: "memory");
        else            asm volatile("s_waitcnt vmcnt(0)" ::: "memory");
        __builtin_amdgcn_s_barrier();
        p ^= 1;
    }

    // epilogue: C/D layout col = lane&15, row = quad*4 + reg
#pragma unroll
    for (int i = 0; i < 4; ++i) {
        const int mb = m0 + wm * 64 + i * 16 + quad * 4;
#pragma unroll
        for (int j = 0; j < 4; ++j) {
            const int n = n0 + wn * 64 + j * 16 + l16;
            const float bv = be[n];
#pragma unroll
            for (int r = 0; r < 4; ++r) {
                const int m = mb + r;
                float v = acc[i][j][r] + bv;
                if (MODE == 0) {
                    v = v > 0.0f ? v : 0.0f;
                    outH[(size_t)(off + m) * N + n] = (f16)v;
                } else {
                    if (outH) {  // sparse: f16 segment write (padded rows ok)
                        outH[(size_t)(off + m) * N + n] = (f16)v;
                    } else if (m < cnt) {  // dense fallback: weighted atomic
                        atomicAdd(&outF[(size_t)m * N + n], wts[m * 4 + e] * v);
                    }
                }
            }
        }
    }
}

// ---------------- combine: out[t] = w1*yseg[p1] + w2*yseg[p2] --------------
__global__ __launch_bounds__(256) void combine_kernel(
    const f16* __restrict__ yseg, const int2* __restrict__ slotmap,
    const float2* __restrict__ wpair, float* __restrict__ out, int aux_idx) {
    const int t = blockIdx.x;
    const int2 p = slotmap[t];
    const float2 w = wpair[t];
    const int d = threadIdx.x * 4;
    const f16x4 a = *(const f16x4*)&yseg[(size_t)p.x * DDIM + d];
    const f16x4 b = *(const f16x4*)&yseg[(size_t)p.y * DDIM + d];
    float4 o;
    o.x = w.x * (float)a[0] + w.y * (float)b[0];
    o.y = w.x * (float)a[1] + w.y * (float)b[1];
    o.z = w.x * (float)a[2] + w.y * (float)b[2];
    o.w = w.x * (float)a[3] + w.y * (float)b[3];
    *(float4*)&out[(size_t)t * DDIM + d] = o;
    if (t == 0 && threadIdx.x == 0 && aux_idx >= 0) out[aux_idx] = 0.0f;
}

extern "C" void kernel_launch(void* const* d_in, const int* in_sizes, int n_in,
                              void* d_out, int out_size, void* d_ws, size_t ws_size,
                              hipStream_t stream) {
    (void)in_sizes; (void)n_in;
    const float* x  = (const float*)d_in[0];
    const float* Wr = (const float*)d_in[1];
    const float* W1 = (const float*)d_in[2];
    const float* b1 = (const float*)d_in[3];
    const float* W2 = (const float*)d_in[4];
    const float* b2 = (const float*)d_in[5];
    float* out = (float*)d_out;

    char* ws = (char*)d_ws;
    float*  wts   = (float*)ws;                     // [0,128K)
    int*    meta  = (int*)(ws + (128 << 10));       // [128K,132K)
    int*    top2  = (int*)(ws + (132 << 10));       // [132K,164K)
    int*    tokl  = (int*)(ws + (164 << 10));       // [164K,232K) TOTPAD ints
    float2* wpair = (float2*)(ws + (240 << 10));    // [240K,304K)
    int2*   slotm = (int2*)(ws + (304 << 10));      // [304K,368K)
    f16*    xb    = (f16*)(ws + (512 << 10));       // 16 MB
    const size_t MBs = 1ull << 20;
    const size_t base = (512 << 10) + 16 * MBs;

    const size_t SPARSE_NEED = (512 << 10) + 80 * MBs + (size_t)TOTPAD * HDIM * sizeof(f16);
    const bool sparse = ws_size >= SPARSE_NEED;

    const int aux_idx = (out_size == M_TOK * DDIM + 1) ? (M_TOK * DDIM) : -1;

    f16 *w1t, *w2t, *h, *yseg;
    if (sparse) {
        w1t  = (f16*)(ws + base);             // 32 MB [E] plain [N][K]
        w2t  = (f16*)(ws + base + 32 * MBs);  // 32 MB [E] plain [N][K]
        h    = (f16*)(ws + base + 64 * MBs);  // 136 MB (TOTPAD x HDIM)
        yseg = (f16*)(ws + (512 << 10));      // 35.7 MB overlay on xb+w1t
                                              // (both dead before gemm<1> runs)
    } else {
        w1t = (f16*)(ws + base);             // 8 MB, per-expert reuse
        w2t = (f16*)(ws + base + 8 * MBs);   // 8 MB
        h   = (f16*)(ws + base + 16 * MBs);  // 64 MB
        yseg = nullptr;
    }

    router_kernel<<<M_TOK / 4, 256, 0, stream>>>(x, Wr, wts, top2, wpair, xb);

    if (sparse) {
        hipMemsetAsync(meta, 0, 16 * sizeof(int), stream);
        hipMemsetAsync(tokl, 0, (size_t)TOTPAD * sizeof(int), stream);
        count_kernel<<<M_TOK / 256, 256, 0, stream>>>(top2, meta);
        fill_kernel<<<M_TOK / 256, 256, 0, stream>>>(top2, meta, tokl, slotm);
        // plain [N][K] weight packs
        pack_nk_kernel<<<dim3(HDIM / 64, DDIM / 64, NEXP), 256, 0, stream>>>(W1, w1t, DDIM, HDIM);
        pack_nk_kernel<<<dim3(DDIM / 64, HDIM / 64, NEXP), 256, 0, stream>>>(W2, w2t, HDIM, DDIM);
        // h = relu(x_gather @ W1 + b1): 256^2 kernel (1056 blocks, ~82% busy)
        gemm256_kernel<0><<<dim3(TOTPAD / 256, HDIM / 256, NEXP), 512, 0, stream>>>(
            xb, w1t, HDIM, DDIM, b1, h, nullptr, wts, tokl, meta, 0);
        // yseg = h @ W2 + b2: 128^2 kernel (1040+ blocks at 2/CU)
        gemm128_kernel<1><<<dim3(TOTPAD / 128, DDIM / 128, NEXP), 256, 0, stream>>>(
            h, w2t, DDIM, HDIM, b2, yseg, nullptr, wts, nullptr, meta, 0);
        combine_kernel<<<M_TOK, 256, 0, stream>>>(yseg, slotm, wpair, out, aux_idx);
    } else {
        hipMemsetAsync(out, 0, (size_t)out_size * sizeof(float), stream);
        for (int e = 0; e < NEXP; ++e) {
            pack_nk_kernel<<<dim3(HDIM / 64, DDIM / 64, 1), 256, 0, stream>>>(
                W1 + (size_t)e * DDIM * HDIM, w1t, DDIM, HDIM);
            gemm128_kernel<0><<<dim3(M_TOK / 128, HDIM / 128, 1), 256, 0, stream>>>(
                xb, w1t, HDIM, DDIM, b1 + (size_t)e * HDIM, h, nullptr, wts, nullptr, nullptr, e);
            pack_nk_kernel<<<dim3(DDIM / 64, HDIM / 64, 1), 256, 0, stream>>>(
                W2 + (size_t)e * HDIM * DDIM, w2t, HDIM, DDIM);
            gemm128_kernel<1><<<dim3(M_TOK / 128, DDIM / 128, 1), 256, 0, stream>>>(
                h, w2t, DDIM, HDIM, b2 + (size_t)e * DDIM, nullptr, out, wts, nullptr, nullptr, e);
        }
    }
}